// Round 6
// baseline (863.404 us; speedup 1.0000x reference)
//
#include <hip/hip_runtime.h>
#include <hip/hip_fp16.h>
#include <cstdint>

#define T_STEPS 512
#define HDIM    256
#define ROWS    8
#define LN_EPS  1e-5f

typedef _Float16 half8   __attribute__((ext_vector_type(8)));
typedef _Float16 half4v  __attribute__((ext_vector_type(4)));
typedef float    float4v __attribute__((ext_vector_type(4)));
typedef float    float2v __attribute__((ext_vector_type(2)));
typedef uint32_t u32x4   __attribute__((ext_vector_type(4)));

// LDS 47 KB. One barrier per step; no global ops in the t-loop. Ah/Al/red
// double-buffered. 8 real rows; fragment reads are PAIR-SPLIT: lane l (bit3=0)
// loads the hi-chunk, lane l+8 loads the lo-chunk of the same (row,kt,q), and
// the pair exchanges via v_mov_dpp row_ror:8 (partner = lane^8 within the
// 16-row). This makes all 64 lanes of a ds_read_b128 address-unique (1024 B
// per instruction instead of 512 B) and halves the dominant DS-pipe term.
struct __align__(16) Smem {
  _Float16 Ah[2][8][264];   // 8448 B  g_hi = fp16(gamma*tanh)   [Al = Ah + 4224 halves]
  _Float16 Al[2][8][264];   // 8448 B  g_lo * 2^11
  float    gb[10][268];     // 10720 B gb[v][n] = tanh(v*we+be)@W + bu + beta@W
  float    wg[260];         // 1040 B  gamma @ W (deferred-LN mu term)
  float    wb[260];         // 1040 B  beta @ W
  float    red[2][8][20];   // 2560 B  LN partials: [buf][row][2w]=S, [2w+1]=Sq
  int      xi[8][516];      // 16512 B clamped x indices (+pad col for t+1 prefetch)
};

__device__ __forceinline__ float tanh_fast(float x) {
  float e = __expf(2.0f * x);
  float r = __builtin_amdgcn_rcpf(e + 1.0f);
  return fmaf(-2.0f, r, 1.0f);
}

// partner value within each 16-lane row: lane i <- lane (i+8) mod 16 (== i^8)
__device__ __forceinline__ float dpp_ror8_f(float v) {
  return __builtin_bit_cast(float,
      __builtin_amdgcn_mov_dpp(__builtin_bit_cast(int, v), 0x128, 0xf, 0xf, true));
}

__global__ __launch_bounds__(512, 1)
void rnn_scan_kernel(const float* __restrict__ x,
                     const float* __restrict__ we,  const float* __restrict__ be,
                     const float* __restrict__ Wu,  const float* __restrict__ bu,
                     const float* __restrict__ gma, const float* __restrict__ bta,
                     const float* __restrict__ Wo,  const float* __restrict__ bo,
                     float* __restrict__ out)
{
  __shared__ Smem sm;
  const int tid = threadIdx.x;
  const int wv  = tid >> 6;        // wave 0..7, owns n in [32*wv, 32*wv+32)
  const int l   = tid & 63;
  const int q   = l >> 4;
  const int m   = l & 15;
  const int sel = m >> 3;          // which of the wave's two n-subtiles this lane finalizes
  const int r   = m & 7;           // real batch row within tile
  const bool isLo = (l & 8) != 0;  // pair-split role for fragment loads
  const int r0  = blockIdx.x * ROWS;

  // ---- init 0: x -> clamped int indices in LDS (the ONLY x reads) ----
  for (int i = tid; i < ROWS * T_STEPS; i += 512) {
    const int rr = i >> 9, c = i & (T_STEPS - 1);
    int xv = (int)x[(size_t)(r0 + rr) * T_STEPS + c];
    xv = xv < 0 ? 0 : (xv > 9 ? 9 : xv);
    sm.xi[rr][c] = xv;
  }
  if (tid < ROWS) sm.xi[tid][T_STEPS] = 0;   // t+1 prefetch pad

  // ---- init 1: embed-tanh table in (to-be-zeroed) Ah/Al space ----
  float* et = reinterpret_cast<float*>(&sm.Ah[0][0][0]);   // 10240 B < 16896 B
  if (tid < HDIM) {
    const float wek = we[tid], bek = be[tid];
    #pragma unroll
    for (int v = 0; v < 10; ++v)
      et[v*HDIM + tid] = tanh_fast(fmaf((float)v, wek, bek));
  }
  __syncthreads();

  // ---- init 2: gb = et@W + bu ; wg = gamma@W ; wb = beta@W ----
  {
    const int g = tid >> 8;        // 0: v=0..4 + wg, 1: v=5..9 + wb
    const int n = tid & 255;
    float acc[5] = {0,0,0,0,0};
    float accx = 0.0f;
    const int vb = g * 5;
    for (int k = 0; k < HDIM; ++k) {
      const float wk = Wu[(size_t)k*HDIM + n];
      #pragma unroll
      for (int v = 0; v < 5; ++v) acc[v] = fmaf(et[(vb+v)*HDIM + k], wk, acc[v]);
      const float xk = g ? bta[k] : gma[k];
      accx = fmaf(xk, wk, accx);
    }
    const float bun = bu[n];
    #pragma unroll
    for (int v = 0; v < 5; ++v) sm.gb[vb+v][n] = acc[v] + bun;
    if (g == 0) sm.wg[n] = accx; else sm.wb[n] = accx;
  }
  __syncthreads();

  // ---- init 3: fold beta@W into gb (beta==0 here; kept general), zero bufs ----
  if (tid < HDIM) {
    const float wbn = sm.wb[tid];
    #pragma unroll
    for (int v = 0; v < 10; ++v) sm.gb[v][tid] += wbn;
  }
  {
    // Ah+Al, BOTH buffers = 8448 halves = 4224 dwords (R3 lesson: not 8448 dw)
    uint32_t* p = reinterpret_cast<uint32_t*>(&sm.Ah[0][0][0]);
    for (int i = tid; i < 4224; i += 512) p[i] = 0u;
  }
  if (tid < 320) (&sm.red[0][0][0])[tid] = 0.0f;

  // ---- persistent W fragments: full K, this wave's two 16-wide n-tiles ----
  // A'[n][k]: lane holds n = 32*wv + nt*16 + m, k = kt*32 + q*8 + j (128 regs,
  // spill into AGPRs is fine: MFMA reads A-operand from AGPR natively)
  half8 Whi[2][8], Wlo[2][8];
  #pragma unroll
  for (int nt = 0; nt < 2; ++nt) {
    const int n = wv*32 + nt*16 + m;
    #pragma unroll
    for (int kt = 0; kt < 8; ++kt) {
      const int k0 = kt*32 + q*8;
      half8 hi, lo;
      #pragma unroll
      for (int j = 0; j < 8; ++j) {
        float v = Wu[(size_t)(k0 + j)*HDIM + n];           // L2-hot across blocks
        _Float16 h = (_Float16)v;
        hi[j] = h;
        lo[j] = (_Float16)((v - (float)h) * 2048.0f);
      }
      Whi[nt][kt] = hi; Wlo[nt][kt] = lo;
    }
  }
  const int n_sel = wv*32 + sel*16 + q*4;    // this lane's 4 finalized columns
  const float4v gmr = *reinterpret_cast<const float4v*>(&gma[n_sel]);
  __syncthreads();                            // wg/gb/xi ready, buffers zeroed
  const float4v wgr = *reinterpret_cast<const float4v*>(&sm.wg[n_sel]);

  const float c1 = 4.8828125e-4f;             // 2^-11
  const float* gbp = &sm.gb[0][n_sel];
  float4v th4;                                // last tanh outputs (epilogue)

  // software prefetch: x-index and gb bias row issued >=1 full step early
  int     xv_n  = sm.xi[r][0];
  float4v gbv_n = *reinterpret_cast<const float4v*>(gbp + xv_n*268);

  #pragma unroll 2
  for (int t = 0; t < T_STEPS; ++t) {
    const int rb = t & 1, wb = rb ^ 1;

    // issue red reads NOW, consume after the MFMA loop (latency overlapped)
    const float* rp = &sm.red[rb][r][0];
    const float4v ra  = *reinterpret_cast<const float4v*>(rp);
    const float4v rbv = *reinterpret_cast<const float4v*>(rp + 4);
    const float4v rc  = *reinterpret_cast<const float4v*>(rp + 8);
    const float4v rd  = *reinterpret_cast<const float4v*>(rp + 12);

    const float4v gbv = gbv_n;                 // bias row for THIS step
    const int xv2 = sm.xi[r][t + 1];           // prefetch next x index

    // MFMA phase, pair-split fragment loads:
    // bit3=0 lanes read hi-chunk, bit3=1 read lo-chunk (Al = Ah + 4224 halves);
    // v_mov_dpp row_ror:8 fetches the partner's chunk; cndmask restores roles.
    const _Float16* ph = &sm.Ah[rb][r][0];
    const _Float16* pb = ph + (isLo ? 4224 : 0);
    float4v a0[2], a1a[2], a1b[2];
    a0[0] = 0.0f; a0[1] = 0.0f;
    a1a[0] = 0.0f; a1a[1] = 0.0f;
    a1b[0] = 0.0f; a1b[1] = 0.0f;
    #pragma unroll
    for (int kt = 0; kt < 8; ++kt) {
      const u32x4 own = *reinterpret_cast<const u32x4*>(pb + kt*32 + q*8);
      u32x4 oth, uh, ul;
      #pragma unroll
      for (int d = 0; d < 4; ++d)
        oth[d] = (uint32_t)__builtin_amdgcn_mov_dpp((int)own[d], 0x128, 0xf, 0xf, true);
      #pragma unroll
      for (int d = 0; d < 4; ++d) {
        uh[d] = isLo ? oth[d] : own[d];
        ul[d] = isLo ? own[d] : oth[d];
      }
      const half8 bhi = __builtin_bit_cast(half8, uh);
      const half8 blo = __builtin_bit_cast(half8, ul);
      a0[0]  = __builtin_amdgcn_mfma_f32_16x16x32_f16(Whi[0][kt], bhi, a0[0],  0, 0, 0);
      a0[1]  = __builtin_amdgcn_mfma_f32_16x16x32_f16(Whi[1][kt], bhi, a0[1],  0, 0, 0);
      a1a[0] = __builtin_amdgcn_mfma_f32_16x16x32_f16(Wlo[0][kt], bhi, a1a[0], 0, 0, 0);
      a1a[1] = __builtin_amdgcn_mfma_f32_16x16x32_f16(Wlo[1][kt], bhi, a1a[1], 0, 0, 0);
      a1b[0] = __builtin_amdgcn_mfma_f32_16x16x32_f16(Whi[0][kt], blo, a1b[0], 0, 0, 0);
      a1b[1] = __builtin_amdgcn_mfma_f32_16x16x32_f16(Whi[1][kt], blo, a1b[1], 0, 0, 0);
    }

    // prefetch gb row for step t+1 (consumed next iteration)
    gbv_n = *reinterpret_cast<const float4v*>(gbp + xv2*268);

    // LN stats of th(t-1): pairs (S,Sq) at even/odd dwords
    const float S  = ((ra[0]+ra[2])+(rbv[0]+rbv[2])) + ((rc[0]+rc[2])+(rd[0]+rd[2]));
    const float Sq = ((ra[1]+ra[3])+(rbv[1]+rbv[3])) + ((rc[1]+rc[3])+(rd[1]+rd[3]));
    const float mu  = S * (1.0f/256.0f);
    const float var = fmaf(Sq, 1.0f/256.0f, -mu*mu);
    const float rs  = __builtin_amdgcn_rsqf(var + LN_EPS);
    const float nrsmu = -rs * mu;
    const float rsc   = rs * c1;

    // tail (dedup): each lane finalizes 4 elements of row r, subtile sel
    float4v A0, A1;
    if (sel) { A0 = a0[1]; A1 = a1a[1] + a1b[1]; }
    else     { A0 = a0[0]; A1 = a1a[0] + a1b[0]; }
    float s = 0.0f, sq = 0.0f;
    half4v hi4, lo4;
    #pragma unroll
    for (int e = 0; e < 4; ++e) {
      const float base = fmaf(nrsmu, wgr[e], gbv[e]);
      const float pre  = fmaf(A0[e], rs, fmaf(A1[e], rsc, base));
      const float th   = tanh_fast(pre);
      th4[e] = th; s += th; sq = fmaf(th, th, sq);
      const float g2 = th * gmr[e];
      const _Float16 h16 = (_Float16)g2;
      hi4[e] = h16;
      lo4[e] = (_Float16)((g2 - (float)h16) * 2048.0f);
    }
    // xor8 via DPP (VALU), xor16/32 via shfl (DS) — sums lane bits {3,4,5}
    s  += dpp_ror8_f(s);   sq += dpp_ror8_f(sq);
    s  += __shfl_xor(s, 16, 64);  s  += __shfl_xor(s, 32, 64);
    sq += __shfl_xor(sq, 16, 64); sq += __shfl_xor(sq, 32, 64);

    *reinterpret_cast<half4v*>(&sm.Ah[wb][r][n_sel]) = hi4;
    *reinterpret_cast<half4v*>(&sm.Al[wb][r][n_sel]) = lo4;
    if (l < 8) {
      float2v p2; p2[0] = s; p2[1] = sq;
      *reinterpret_cast<float2v*>(&sm.red[wb][l][2*wv]) = p2;   // one b64
    }
    xv_n = xv2;
    __syncthreads();                           // the ONLY barrier per step
  }

  // ---- epilogue: final LN (stats in red[0]), h_final in gb space, out GEMM ----
  float mu, rs;
  {
    const float* rp = &sm.red[0][r][0];
    const float4v ra  = *reinterpret_cast<const float4v*>(rp);
    const float4v rbv = *reinterpret_cast<const float4v*>(rp + 4);
    const float4v rc  = *reinterpret_cast<const float4v*>(rp + 8);
    const float4v rd  = *reinterpret_cast<const float4v*>(rp + 12);
    const float S  = ((ra[0]+ra[2])+(rbv[0]+rbv[2])) + ((rc[0]+rc[2])+(rd[0]+rd[2]));
    const float Sq = ((ra[1]+ra[3])+(rbv[1]+rbv[3])) + ((rc[1]+rc[3])+(rd[1]+rd[3]));
    mu = S * (1.0f/256.0f);
    const float var = fmaf(Sq, 1.0f/256.0f, -mu*mu);
    rs = __builtin_amdgcn_rsqf(var + LN_EPS);
  }
  float* hf = reinterpret_cast<float*>(&sm.gb[0][0]);   // gb dead after loop
  {
    const float4v btv = *reinterpret_cast<const float4v*>(&bta[n_sel]);
    float4v h4;
    #pragma unroll
    for (int e = 0; e < 4; ++e)
      h4[e] = fmaf((th4[e] - mu) * rs, gmr[e], btv[e]);
    *reinterpret_cast<float4v*>(&hf[r*260 + n_sel]) = h4;
  }
  __syncthreads();
  if (tid < ROWS*10) {
    const int rr = tid / 10, o = tid % 10;
    float acc = bo[o];
    #pragma unroll 4
    for (int n = 0; n < HDIM; ++n)
      acc = fmaf(hf[rr*260 + n], Wo[n*10 + o], acc);
    out[(size_t)(r0 + rr)*10 + o] = acc;
  }
}

extern "C" void kernel_launch(void* const* d_in, const int* in_sizes, int n_in,
                              void* d_out, int out_size, void* d_ws, size_t ws_size,
                              hipStream_t stream) {
  const float* x  = (const float*)d_in[0];
  const float* we = (const float*)d_in[1];
  const float* be = (const float*)d_in[2];
  const float* Wu = (const float*)d_in[3];
  const float* bu = (const float*)d_in[4];
  const float* ga = (const float*)d_in[5];
  const float* bt = (const float*)d_in[6];
  const float* Wo = (const float*)d_in[7];
  const float* bo = (const float*)d_in[8];
  const int B = in_sizes[0] / T_STEPS;          // 2048
  dim3 grid(B / ROWS), block(512);
  rnn_scan_kernel<<<grid, block, 0, stream>>>(x, we, be, Wu, bu, ga, bt, Wo, bo,
                                              (float*)d_out);
}